// Round 11
// baseline (532.122 us; speedup 1.0000x reference)
//
#include <hip/hip_runtime.h>
#include <math.h>

#define B_  16
#define F_  64
#define C_  64
#define M_  512
#define OC_ 32

typedef float vf4 __attribute__((ext_vector_type(4)));   // clang-native for nt st

// ---------------------------------------------------------------------------
// k1 diag: R3/R9 structure (plain x loads), body repeated nreps times
// (idempotent; opaque0==0 defeats cross-pass CSE). Pass 2+ is L1/L2-hot.
// ---------------------------------------------------------------------------
__global__ __launch_bounds__(128, 6) void k1_mean(
    const float* __restrict__ x,
    float* __restrict__ s_out, float* __restrict__ rpart,
    int nreps, int opaque0)
{
    const int gid = blockIdx.x;        // bc*4 + q
    const int q   = gid & 3;
    const int bc  = gid >> 2;
    const int b   = bc >> 6;
    const int c   = bc & 63;
    const int t   = threadIdx.x;
    const int tf  = t >> 5;            // 0..3 -> f chunk
    const int tm  = t & 31;            // float4 column within window
    const size_t rowbase = ((size_t)b * F_ * C_ + c) * M_;   // + f*C*M

    __shared__ float4 red[4][32];

    for (int rep = 0; rep < nreps; ++rep) {
        const int m4 = (q << 5) + tm + rep * opaque0;  // runtime 0 offset
        float ax = 0.f, ay = 0.f, az = 0.f, aw = 0.f;
        #pragma unroll 8
        for (int j = 0; j < 16; ++j) {
            const int f = (tf << 4) + j;
            const float4 v = ((const float4*)(x + rowbase + (size_t)f * C_ * M_))[m4];
            ax += v.x; ay += v.y; az += v.z; aw += v.w;
        }
        red[tf][tm] = make_float4(ax, ay, az, aw);
        __syncthreads();

        if (tf == 0) {
            const float4 r1 = red[1][tm], r2 = red[2][tm], r3 = red[3][tm];
            const float inv_f = 1.0f / (float)F_;
            float4 sv;
            sv.x = (ax + r1.x + r2.x + r3.x) * inv_f;
            sv.y = (ay + r1.y + r2.y + r3.y) * inv_f;
            sv.z = (az + r1.z + r2.z + r3.z) * inv_f;
            sv.w = (aw + r1.w + r2.w + r3.w) * inv_f;
            ((float4*)(s_out + (size_t)bc * M_))[m4] = sv;

            float p = sv.x + sv.y + sv.z + sv.w;
            #pragma unroll
            for (int off = 16; off > 0; off >>= 1) p += __shfl_xor(p, off);
            if (t == 0) rpart[gid] = p;
        }
        __syncthreads();               // red[] reuse fence for next pass
    }
}

// ---------------------------------------------------------------------------
// k2 diag: R3 structure, stage+reduce repeated nreps times (R6 pattern).
// ---------------------------------------------------------------------------
__global__ __launch_bounds__(256) void k2_laplace(
    const float* __restrict__ A, const float* __restrict__ phys,
    const float* __restrict__ kappa_p, const float* __restrict__ alpha_p,
    const float* __restrict__ s_in, const float* __restrict__ rpart,
    const float* __restrict__ w1, const float* __restrict__ b1,
    const float* __restrict__ w2, const float* __restrict__ b2,
    float* __restrict__ snew, int nreps, int opaque0)
{
    __shared__ float Al[C_ * 65];
    __shared__ float sl[C_];
    __shared__ float redD[4 * C_];
    __shared__ float redA[4 * C_];

    const int bm = blockIdx.x;     // b*M + m
    const int b  = bm >> 9;
    const int m  = bm & 511;
    const int t  = threadIdx.x;    // 0..255
    const int c  = t & 63;
    const int q  = t >> 6;

    float r = 0.f;
    if (t < 64) {
        const float4 rp = ((const float4*)rpart)[b * C_ + t];
        const float rin = (rp.x + rp.y + rp.z + rp.w) * (1.0f / (float)M_);
        r = b2[0];
        #pragma unroll
        for (int j = 0; j < 16; ++j) {
            float h = rin * w1[j] + b1[j];        // w1 is (16,1)
            h = (h > 0.f) ? h : (expf(h) - 1.f);  // ELU(alpha=1)
            r += h * w2[j];
        }
        sl[t] = s_in[((size_t)b * C_ + t) * M_ + m];
    }

    const float4* Ap = (const float4*)(A + (size_t)bm * (C_ * C_));

    for (int rep = 0; rep < nreps; ++rep) {
        #pragma unroll
        for (int i = 0; i < 4; ++i) {
            const int idx = t + i * 256 + rep * opaque0;  // runtime 0
            const float4 v = Ap[idx];
            const int row = idx >> 4;
            const int col = (idx & 15) << 2;
            float* dst = &Al[row * 65 + col];
            dst[0] = v.x; dst[1] = v.y; dst[2] = v.z; dst[3] = v.w;
        }
        __syncthreads();

        float dpart = 0.f, apart = 0.f;
        const int j0 = q << 4;
        #pragma unroll
        for (int j = 0; j < 16; ++j) {
            dpart += Al[c * 65 + (j0 + j)];              // row c (deg)
            apart += Al[(j0 + j) * 65 + c] * sl[j0 + j]; // col c (A^T s)
        }
        redD[(q << 6) + c] = dpart;
        redA[(q << 6) + c] = apart;
        __syncthreads();
    }

    if (t < 64) {
        const float deg = redD[t] + redD[64 + t] + redD[128 + t] + redD[192 + t];
        const float As  = redA[t] + redA[64 + t] + redA[128 + t] + redA[192 + t];
        const float sval = sl[t];
        const float k    = log1pf(expf(kappa_p[0]));   // softplus
        const float Ls   = deg * sval - As;
        const float val  = sval - k * Ls
                         + (r + alpha_p[0] * phys[((size_t)b * C_ + t) * M_ + m]);
        snew[((size_t)b * C_ + t) * M_ + m] = val;
    }
}

// ---------------------------------------------------------------------------
// k3 diag: nt-store expansion, whole grid-stride loop repeated nreps times.
// Every pass re-pays the HBM store (nt), so marginal = true store cost.
// ---------------------------------------------------------------------------
__global__ __launch_bounds__(256) void k3_expand(
    const float* __restrict__ snew,
    const float* __restrict__ pw, const float* __restrict__ pb,
    float* __restrict__ out, int nreps, int opaque0)
{
    const int n4 = (B_ * OC_ * C_ * M_) / 4;   // 4,194,304
    for (int rep = 0; rep < nreps; ++rep) {
        const int ofs = rep * opaque0;         // runtime 0
        for (int i = blockIdx.x * blockDim.x + threadIdx.x; i < n4;
             i += gridDim.x * blockDim.x) {
            const int ii = i + ofs;
            const int m4 = ii & 127;           // M/4 = 128
            const int c  = (ii >> 7) & 63;
            const int o  = (ii >> 13) & 31;
            const int b  = ii >> 18;
            const float4 v = ((const float4*)snew)[(((b << 6) + c) << 7) + m4];
            const float w  = pw[o];
            const float bb = pb[o];
            vf4 r;
            r.x = v.x * w + bb; r.y = v.y * w + bb;
            r.z = v.z * w + bb; r.w = v.w * w + bb;
            __builtin_nontemporal_store(r, ((vf4*)out) + ii);
        }
    }
}

extern "C" void kernel_launch(void* const* d_in, const int* in_sizes, int n_in,
                              void* d_out, int out_size, void* d_ws, size_t ws_size,
                              hipStream_t stream)
{
    const float* x     = (const float*)d_in[0];
    const float* A     = (const float*)d_in[1];
    const float* phys  = (const float*)d_in[2];
    const float* kappa = (const float*)d_in[3];
    const float* alpha = (const float*)d_in[4];
    const float* w1    = (const float*)d_in[5];
    const float* b1    = (const float*)d_in[6];
    const float* w2    = (const float*)d_in[7];
    const float* b2    = (const float*)d_in[8];
    const float* pw    = (const float*)d_in[9];
    const float* pb    = (const float*)d_in[10];
    float* out = (float*)d_out;

    float* ws    = (float*)d_ws;
    float* s     = ws;                            // B*C*M
    float* snew  = ws + (size_t)B_ * C_ * M_;     // B*C*M
    float* rpart = ws + (size_t)2 * B_ * C_ * M_; // B*C*4 (16B-aligned)

    k1_mean<<<B_ * C_ * 4, 128, 0, stream>>>(x, s, rpart,
                                             /*nreps=*/16, /*opaque0=*/0);
    k2_laplace<<<B_ * M_, 256, 0, stream>>>(A, phys, kappa, alpha, s, rpart,
                                            w1, b1, w2, b2, snew,
                                            /*nreps=*/12, /*opaque0=*/0);
    k3_expand<<<2048, 256, 0, stream>>>(snew, pw, pb, out,
                                        /*nreps=*/12, /*opaque0=*/0);
}

// Round 12
// 67.536 us; speedup vs baseline: 7.8791x; 7.8791x over previous
//
#include <hip/hip_runtime.h>
#include <math.h>

#define B_  16
#define F_  64
#define C_  64
#define M_  512
#define OC_ 32

typedef float vf4 __attribute__((ext_vector_type(4)));   // clang-native for nt st

// ---------------------------------------------------------------------------
// k1: s[b,c,m] = mean_f x[b,f,c,m], m-split 4-ways. (R9 version — at its
// HBM floor per R11 diagnostic: 16-pass uniform 17.7 µs/pass, floor 21.3.)
// ---------------------------------------------------------------------------
__global__ __launch_bounds__(128, 6) void k1_mean(
    const float* __restrict__ x,
    float* __restrict__ s_out, float* __restrict__ rpart)
{
    const int gid = blockIdx.x;        // bc*4 + q
    const int q   = gid & 3;
    const int bc  = gid >> 2;
    const int b   = bc >> 6;
    const int c   = bc & 63;
    const int t   = threadIdx.x;
    const int tf  = t >> 5;            // 0..3 -> f chunk
    const int tm  = t & 31;            // float4 column within window
    const int m4  = (q << 5) + tm;     // global float4 index 0..127

    const size_t rowbase = ((size_t)b * F_ * C_ + c) * M_;   // + f*C*M
    float ax = 0.f, ay = 0.f, az = 0.f, aw = 0.f;
    #pragma unroll 8
    for (int j = 0; j < 16; ++j) {
        const int f = (tf << 4) + j;
        const float4 v = ((const float4*)(x + rowbase + (size_t)f * C_ * M_))[m4];
        ax += v.x; ay += v.y; az += v.z; aw += v.w;
    }

    __shared__ float4 red[4][32];
    red[tf][tm] = make_float4(ax, ay, az, aw);
    __syncthreads();

    if (tf == 0) {                     // lanes 0..31 of wave 0
        const float4 r1 = red[1][tm], r2 = red[2][tm], r3 = red[3][tm];
        const float inv_f = 1.0f / (float)F_;
        float4 sv;
        sv.x = (ax + r1.x + r2.x + r3.x) * inv_f;
        sv.y = (ay + r1.y + r2.y + r3.y) * inv_f;
        sv.z = (az + r1.z + r2.z + r3.z) * inv_f;
        sv.w = (aw + r1.w + r2.w + r3.w) * inv_f;
        ((float4*)(s_out + (size_t)bc * M_))[m4] = sv;

        float p = sv.x + sv.y + sv.z + sv.w;
        #pragma unroll
        for (int off = 16; off > 0; off >>= 1) p += __shfl_xor(p, off);
        if (t == 0) rpart[gid] = p;
    }
}

// ---------------------------------------------------------------------------
// k2 v6: R3 structure, but snew is written TRANSPOSED snew_T[b][m][c]:
// one contiguous 256 B store-run per block (single writer per cache line)
// instead of 64 x 4 B at stride 2 KB (dirty-line ping-pong across XCDs).
// ---------------------------------------------------------------------------
__global__ __launch_bounds__(256) void k2_laplace(
    const float* __restrict__ A, const float* __restrict__ phys,
    const float* __restrict__ kappa_p, const float* __restrict__ alpha_p,
    const float* __restrict__ s_in, const float* __restrict__ rpart,
    const float* __restrict__ w1, const float* __restrict__ b1,
    const float* __restrict__ w2, const float* __restrict__ b2,
    float* __restrict__ snewT)
{
    __shared__ float Al[C_ * 65];
    __shared__ float sl[C_];
    __shared__ float redD[4 * C_];
    __shared__ float redA[4 * C_];

    const int bm = blockIdx.x;     // b*M + m
    const int b  = bm >> 9;
    const int m  = bm & 511;
    const int t  = threadIdx.x;    // 0..255
    const int c  = t & 63;
    const int q  = t >> 6;

    // r-MLP preamble: overlapped by the compiler with the A staging below
    float r = 0.f;
    if (t < 64) {
        const float4 rp = ((const float4*)rpart)[b * C_ + t];
        const float rin = (rp.x + rp.y + rp.z + rp.w) * (1.0f / (float)M_);
        r = b2[0];
        #pragma unroll
        for (int j = 0; j < 16; ++j) {
            float h = rin * w1[j] + b1[j];        // w1 is (16,1)
            h = (h > 0.f) ? h : (expf(h) - 1.f);  // ELU(alpha=1)
            r += h * w2[j];
        }
        sl[t] = s_in[((size_t)b * C_ + t) * M_ + m];
    }

    // stage A[b,m,:,:] (4096 f32) via coalesced float4 loads, pad stride 65
    const float4* Ap = (const float4*)(A + (size_t)bm * (C_ * C_));
    #pragma unroll
    for (int i = 0; i < 4; ++i) {
        const int idx = t + i * 256;       // float4 index 0..1023
        const float4 v = Ap[idx];
        const int row = idx >> 4;          // 16 float4 per row
        const int col = (idx & 15) << 2;
        float* dst = &Al[row * 65 + col];
        dst[0] = v.x; dst[1] = v.y; dst[2] = v.z; dst[3] = v.w;
    }
    __syncthreads();

    // quarter-reductions: q selects 16 of the 64 summation indices
    float dpart = 0.f, apart = 0.f;
    const int j0 = q << 4;
    #pragma unroll
    for (int j = 0; j < 16; ++j) {
        dpart += Al[c * 65 + (j0 + j)];              // row c (deg)
        apart += Al[(j0 + j) * 65 + c] * sl[j0 + j]; // col c (A^T s)
    }
    redD[(q << 6) + c] = dpart;
    redA[(q << 6) + c] = apart;
    __syncthreads();

    if (t < 64) {
        const float deg = redD[t] + redD[64 + t] + redD[128 + t] + redD[192 + t];
        const float As  = redA[t] + redA[64 + t] + redA[128 + t] + redA[192 + t];
        const float sval = sl[t];
        const float k    = log1pf(expf(kappa_p[0]));   // softplus
        const float Ls   = deg * sval - As;
        const float val  = sval - k * Ls
                         + (r + alpha_p[0] * phys[((size_t)b * C_ + t) * M_ + m]);
        snewT[((size_t)bm) * C_ + t] = val;            // [b][m][c] contiguous
    }
}

// ---------------------------------------------------------------------------
// k3 v3: out[b,o,c,m] = snew_T[b,m,c]*pw[o] + pb[o].
// Block = (b, 16-m chunk): stage 16x64 snew_T floats (4 KB) coalesced into
// LDS (pad 65), then thread (c, m-quad) expands over all 32 o with
// non-temporal float4 stores (64 B segments, single writer).
// ---------------------------------------------------------------------------
__global__ __launch_bounds__(256) void k3_expand(
    const float* __restrict__ snewT,
    const float* __restrict__ pw, const float* __restrict__ pb,
    float* __restrict__ out)
{
    __shared__ float sn[16 * 65];

    const int blk = blockIdx.x;      // b*32 + mc
    const int b   = blk >> 5;
    const int m0  = (blk & 31) << 4; // 16-m chunk
    const int t   = threadIdx.x;

    // stage snew_T[b][m0..m0+15][0..63] (256 float4, one per thread)
    {
        const float4 v = ((const float4*)(snewT + ((size_t)(b * M_ + m0)) * C_))[t];
        const int row = t >> 4;          // 16 float4 per row
        const int col = (t & 15) << 2;
        float* dst = &sn[row * 65 + col];
        dst[0] = v.x; dst[1] = v.y; dst[2] = v.z; dst[3] = v.w;
    }
    __syncthreads();

    const int c   = t >> 2;          // 0..63
    const int m4r = t & 3;           // m-quad within chunk
    const float v0 = sn[(4 * m4r + 0) * 65 + c];
    const float v1 = sn[(4 * m4r + 1) * 65 + c];
    const float v2 = sn[(4 * m4r + 2) * 65 + c];
    const float v3 = sn[(4 * m4r + 3) * 65 + c];

    const size_t obase = ((size_t)b * OC_ * C_ + c) * M_ + m0 + (m4r << 2);
    #pragma unroll 8
    for (int o = 0; o < OC_; ++o) {
        const float w  = pw[o];
        const float bb = pb[o];
        vf4 r;
        r.x = v0 * w + bb; r.y = v1 * w + bb;
        r.z = v2 * w + bb; r.w = v3 * w + bb;
        __builtin_nontemporal_store(r, (vf4*)(out + obase + (size_t)o * (C_ * M_)));
    }
}

extern "C" void kernel_launch(void* const* d_in, const int* in_sizes, int n_in,
                              void* d_out, int out_size, void* d_ws, size_t ws_size,
                              hipStream_t stream)
{
    const float* x     = (const float*)d_in[0];
    const float* A     = (const float*)d_in[1];
    const float* phys  = (const float*)d_in[2];
    const float* kappa = (const float*)d_in[3];
    const float* alpha = (const float*)d_in[4];
    const float* w1    = (const float*)d_in[5];
    const float* b1    = (const float*)d_in[6];
    const float* w2    = (const float*)d_in[7];
    const float* b2    = (const float*)d_in[8];
    const float* pw    = (const float*)d_in[9];
    const float* pb    = (const float*)d_in[10];
    float* out = (float*)d_out;

    float* ws    = (float*)d_ws;
    float* s     = ws;                            // B*C*M
    float* snewT = ws + (size_t)B_ * C_ * M_;     // B*M*C (transposed)
    float* rpart = ws + (size_t)2 * B_ * C_ * M_; // B*C*4 (16B-aligned)

    k1_mean<<<B_ * C_ * 4, 128, 0, stream>>>(x, s, rpart);
    k2_laplace<<<B_ * M_, 256, 0, stream>>>(A, phys, kappa, alpha, s, rpart,
                                            w1, b1, w2, b2, snewT);
    k3_expand<<<B_ * (M_ / 16), 256, 0, stream>>>(snewT, pw, pb, out);
}